// Round 1
// baseline (1067.395 us; speedup 1.0000x reference)
//
#include <hip/hip_runtime.h>
#include <hip/hip_bf16.h>

// MonetMoVDE: B=4 T=2048 D=2048 H=8 E=512 M=8, F=4096, HALF=1024
#define TOK   8192   // B*T
#define DD    2048
#define FF    4096
#define EE    512
#define HALF  1024
#define KCAT  8704   // F + F + E  (concat K for V-GEMMs, 8704 = 136*64)

typedef __bf16 bf16x8 __attribute__((ext_vector_type(8)));
typedef __bf16 bf16x4 __attribute__((ext_vector_type(4)));
typedef float  f32x4  __attribute__((ext_vector_type(4)));
using bf16 = __hip_bfloat16;

#define AS1(p) ((const __attribute__((address_space(1))) void*)(p))
#define AS3(p) ((__attribute__((address_space(3))) void*)(p))

// ---------------- prep kernels ----------------

__global__ void cvt_bf16(const float* __restrict__ in, bf16* __restrict__ out, int n4) {
    int i = blockIdx.x * blockDim.x + threadIdx.x;
    int stride = gridDim.x * blockDim.x;
    for (; i < n4; i += stride) {
        float4 v = ((const float4*)in)[i];
        bf16x4 o;
        o[0] = (__bf16)v.x; o[1] = (__bf16)v.y; o[2] = (__bf16)v.z; o[3] = (__bf16)v.w;
        ((bf16x4*)out)[i] = o;
    }
}

// W [1024][8704] = [vA | vB | bT]   (vA,vB: [1024][4096] f32; bmat: [512][1024] f32)
__global__ void pack_w(const float* __restrict__ vA, const float* __restrict__ vB,
                       const float* __restrict__ bmat, bf16* __restrict__ W) {
    int n = blockIdx.x;
    const float* ra = vA + (size_t)n * FF;
    const float* rb = vB + (size_t)n * FF;
    bf16* w = W + (size_t)n * KCAT;
    for (int k = threadIdx.x; k < FF; k += 256) {
        w[k]      = __float2bfloat16(ra[k]);
        w[FF + k] = __float2bfloat16(rb[k]);
    }
    for (int e = threadIdx.x; e < EE; e += 256)
        w[2 * FF + e] = __float2bfloat16(bmat[(size_t)e * HALF + n]);
}

// ---------------- GEMM: C[m,n] = sum_k A[m,k] * Bw[n,k] ----------------
// 128x128 tile, BK=64, 4 waves (2x2), 16x16x32 bf16 MFMA.
// MODE 0: fp32 store.  MODE 1: relu(z+bias)^2 -> bf16 store.
template<int MODE>
__global__ __launch_bounds__(256)
void gemm_bt(const bf16* __restrict__ A, const bf16* __restrict__ Bw,
             const float* __restrict__ bias, void* __restrict__ Cout,
             int N, int K, int ldc)
{
    __shared__ __align__(16) bf16 lsA[128 * 64];
    __shared__ __align__(16) bf16 lsB[128 * 64];
    const int tid  = threadIdx.x;
    const int lane = tid & 63;
    const int wid  = tid >> 6;
    const int wr   = wid >> 1, wc = wid & 1;
    const int nbn  = N >> 7;

    int bid = blockIdx.x;
    {   // bijective XCD swizzle (m204)
        int nwg = gridDim.x;
        int q = nwg >> 3, r = nwg & 7;
        int xcd = bid & 7, idx = bid >> 3;
        bid = (xcd < r ? xcd * (q + 1) : r * (q + 1) + (xcd - r) * q) + idx;
    }
    const int bm = bid / nbn, bn = bid % nbn;
    const long row0 = (long)bm << 7;
    const int  col0 = bn << 7;
    const int  r16 = lane & 15, kb = lane >> 4;

    f32x4 acc[4][4];
    #pragma unroll
    for (int i = 0; i < 4; ++i)
        #pragma unroll
        for (int j = 0; j < 4; ++j)
            acc[i][j] = (f32x4){0.f, 0.f, 0.f, 0.f};

    for (int k0 = 0; k0 < K; k0 += 64) {
        __syncthreads();   // protect LDS from previous iteration's readers
        #pragma unroll
        for (int c = 0; c < 4; ++c) {
            int flat = (c * 256 + tid) * 8;          // element index in 128x64 tile
            int rr = flat >> 6, cc = flat & 63;
            const bf16* srcA = A  + (row0 + rr) * (long)K + k0 + cc;
            const bf16* srcB = Bw + (long)(col0 + rr) * K + k0 + cc;
            bf16* dA = &lsA[(size_t)(c * 256 + (tid & ~63)) * 8];  // wave-uniform base
            bf16* dB = &lsB[(size_t)(c * 256 + (tid & ~63)) * 8];
            __builtin_amdgcn_global_load_lds(AS1(srcA), AS3(dA), 16, 0, 0);
            __builtin_amdgcn_global_load_lds(AS1(srcB), AS3(dB), 16, 0, 0);
        }
        __syncthreads();   // compiler drains vmcnt before barrier
        #pragma unroll
        for (int kk = 0; kk < 2; ++kk) {
            bf16x8 af[4], bfv[4];
            #pragma unroll
            for (int i = 0; i < 4; ++i)
                af[i] = *(const bf16x8*)&lsA[(wr * 64 + i * 16 + r16) * 64 + kk * 32 + kb * 8];
            #pragma unroll
            for (int j = 0; j < 4; ++j)
                bfv[j] = *(const bf16x8*)&lsB[(wc * 64 + j * 16 + r16) * 64 + kk * 32 + kb * 8];
            #pragma unroll
            for (int i = 0; i < 4; ++i)
                #pragma unroll
                for (int j = 0; j < 4; ++j)
                    acc[i][j] = __builtin_amdgcn_mfma_f32_16x16x32_bf16(af[i], bfv[j], acc[i][j], 0, 0, 0);
        }
    }

    // epilogue: C row = row0 + wr*64 + i*16 + (lane>>4)*4 + e ; col = col0 + wc*64 + j*16 + (lane&15)
    const int rbase = wr * 64 + (lane >> 4) * 4;
    #pragma unroll
    for (int i = 0; i < 4; ++i) {
        #pragma unroll
        for (int j = 0; j < 4; ++j) {
            const int cc = col0 + wc * 64 + j * 16 + r16;
            float badd = 0.f;
            if (MODE == 1) badd = bias[cc];
            #pragma unroll
            for (int e = 0; e < 4; ++e) {
                long row = row0 + rbase + i * 16 + e;
                float v = acc[i][j][e];
                if (MODE == 1) {
                    v += badd;
                    v = fmaxf(v, 0.f);
                    v = v * v;
                    ((bf16*)Cout)[row * ldc + cc] = __float2bfloat16(v);
                } else {
                    ((float*)Cout)[row * ldc + cc] = v;
                }
            }
        }
    }
}

// ---------------- glue: per-token gating / tiny einsums ----------------
// In:  g1,g2 [TOK][8][512] f32; Yl[:,0:4096]=x1 raw bf16; Yr[:,4096:8192]=x2 raw bf16
// Out: Yl = [x1*g1s | y12 | g1s]; Yr = [y21 | x2*g2s | g2s]  (all bf16)
#define GPAD 524   // 8-row pad: 524%32=12 -> h-stride hits 8 distinct banks; 524*4%16==0
__global__ __launch_bounds__(256)
void glue(const float* __restrict__ g1, const float* __restrict__ g2,
          bf16* __restrict__ Yl, bf16* __restrict__ Yr)
{
    __shared__ __align__(16) float g1t[8 * GPAD];
    __shared__ __align__(16) float g2t[8 * GPAD];
    __shared__ float g1s[EE], g2s[EE];
    __shared__ float t1s[64], t2s[64];        // [ (m<<3)|h ] stored as [o=lane: h=o&7, m=o>>3]
    __shared__ float t1p[4][64], t2p[4][64];
    __shared__ __align__(16) bf16 x1t[FF], x2t[FF];

    const int t   = blockIdx.x;
    const int tid = threadIdx.x;
    const float* g1p = g1 + (size_t)t * FF;
    const float* g2p = g2 + (size_t)t * FF;
    bf16* ylp = Yl + (size_t)t * KCAT;
    bf16* yrp = Yr + (size_t)t * KCAT;

    // stage g1/g2 with row pad
    #pragma unroll
    for (int c = 0; c < 4; ++c) {
        int idx4 = (c * 256 + tid) * 4;
        float4 v1 = *(const float4*)(g1p + idx4);
        float4 v2 = *(const float4*)(g2p + idx4);
        int h = idx4 >> 9, e = idx4 & 511;
        *(float4*)&g1t[h * GPAD + e] = v1;
        *(float4*)&g2t[h * GPAD + e] = v2;
    }
    // stage x1 (from Yl slot0), x2 (from Yr slot1)
    #pragma unroll
    for (int c = 0; c < 2; ++c) {
        int idx8 = (c * 256 + tid) * 8;
        *(bf16x8*)&x1t[idx8] = *(const bf16x8*)(ylp + idx8);
        *(bf16x8*)&x2t[idx8] = *(const bf16x8*)(yrp + FF + idx8);
    }
    __syncthreads();

    // gate sums over h
    #pragma unroll
    for (int c = 0; c < 2; ++c) {
        int e = c * 256 + tid;
        float s1 = 0.f, s2 = 0.f;
        #pragma unroll
        for (int h = 0; h < 8; ++h) { s1 += g1t[h * GPAD + e]; s2 += g2t[h * GPAD + e]; }
        g1s[e] = s1; g2s[e] = s2;
    }

    // t1[h,m] = sum_e x1[e,m]*g1[h,e] ; t2 likewise with x2,g2. 4-way partials.
    {
        int o = tid & 63;          // h = o&7 varies fastest across lanes (bank spread)
        int h = o & 7, m = o >> 3;
        int p = tid >> 6;
        float s1 = 0.f, s2 = 0.f;
        #pragma unroll 8
        for (int ii = 0; ii < 128; ++ii) {
            int e = p * 128 + ii;
            float xv1 = __bfloat162float(x1t[e * 8 + m]);
            float xv2 = __bfloat162float(x2t[e * 8 + m]);
            s1 += xv1 * g1t[h * GPAD + e];
            s2 += xv2 * g2t[h * GPAD + e];
        }
        t1p[p][o] = s1; t2p[p][o] = s2;
    }
    __syncthreads();
    if (tid < 64)       t1s[tid] = t1p[0][tid] + t1p[1][tid] + t1p[2][tid] + t1p[3][tid];
    else if (tid < 128) { int o = tid - 64; t2s[o] = t2p[0][o] + t2p[1][o] + t2p[2][o] + t2p[3][o]; }
    __syncthreads();

    // y11 = x1*g1s -> Yl[0:4096]; y22 = x2*g2s -> Yr[4096:8192]
    #pragma unroll
    for (int c = 0; c < 2; ++c) {
        int f0 = (c * 256 + tid) * 8;
        int e  = f0 >> 3;
        float s1 = g1s[e], s2 = g2s[e];
        bf16x8 xa = *(const bf16x8*)&x1t[f0];
        bf16x8 xb = *(const bf16x8*)&x2t[f0];
        bf16x8 o1, o2;
        #pragma unroll
        for (int u = 0; u < 8; ++u) {
            o1[u] = (__bf16)((float)xa[u] * s1);
            o2[u] = (__bf16)((float)xb[u] * s2);
        }
        *(bf16x8*)(ylp + f0)      = o1;
        *(bf16x8*)(yrp + FF + f0) = o2;
    }
    // y12[i,m] = sum_h t2[h,m]*g1[h,i] -> Yl[4096:8192]
    // y21[j,m] = sum_h t1[h,m]*g2[h,j] -> Yr[0:4096]
    #pragma unroll
    for (int c = 0; c < 2; ++c) {
        int f0 = (c * 256 + tid) * 8;
        int i  = f0 >> 3;
        bf16x8 o12v, o21v;
        #pragma unroll
        for (int m = 0; m < 8; ++m) {
            float s12 = 0.f, s21 = 0.f;
            #pragma unroll
            for (int h = 0; h < 8; ++h) {
                s12 += t2s[(m << 3) | h] * g1t[h * GPAD + i];
                s21 += t1s[(m << 3) | h] * g2t[h * GPAD + i];
            }
            o12v[m] = (__bf16)s12;
            o21v[m] = (__bf16)s21;
        }
        *(bf16x8*)(ylp + FF + f0) = o12v;
        *(bf16x8*)(yrp + f0)      = o21v;
    }
    // gate tails (bias-GEMM inputs)
    {
        int e0 = tid * 2;
        ylp[2 * FF + e0]     = __float2bfloat16(g1s[e0]);
        ylp[2 * FF + e0 + 1] = __float2bfloat16(g1s[e0 + 1]);
        yrp[2 * FF + e0]     = __float2bfloat16(g2s[e0]);
        yrp[2 * FF + e0 + 1] = __float2bfloat16(g2s[e0 + 1]);
    }
}

// ---------------- launch ----------------

extern "C" void kernel_launch(void* const* d_in, const int* in_sizes, int n_in,
                              void* d_out, int out_size, void* d_ws, size_t ws_size,
                              hipStream_t stream) {
    const float* x    = (const float*)d_in[0];
    const float* g1   = (const float*)d_in[1];
    const float* g2   = (const float*)d_in[2];
    const float* u1_w = (const float*)d_in[3];
    const float* u1_b = (const float*)d_in[4];
    const float* u2_w = (const float*)d_in[5];
    const float* u2_b = (const float*)d_in[6];
    const float* v11  = (const float*)d_in[7];
    const float* v12  = (const float*)d_in[8];
    const float* v21  = (const float*)d_in[9];
    const float* v22  = (const float*)d_in[10];
    const float* b1   = (const float*)d_in[11];
    const float* b2   = (const float*)d_in[12];
    float* out = (float*)d_out;

    size_t off = 0;
    char* base = (char*)d_ws;
    auto take = [&](size_t bytes) { void* p = base + off; off += (bytes + 255) & ~(size_t)255; return p; };
    bf16* Xb  = (bf16*)take((size_t)TOK * DD * 2);
    bf16* U1b = (bf16*)take((size_t)FF * DD * 2);
    bf16* U2b = (bf16*)take((size_t)FF * DD * 2);
    bf16* Wl  = (bf16*)take((size_t)HALF * KCAT * 2);
    bf16* Wr  = (bf16*)take((size_t)HALF * KCAT * 2);
    bf16* Yl  = (bf16*)take((size_t)TOK * KCAT * 2);
    bf16* Yr  = (bf16*)take((size_t)TOK * KCAT * 2);

    // prep
    cvt_bf16<<<4096, 256, 0, stream>>>(x,    Xb,  TOK * DD / 4);
    cvt_bf16<<<2048, 256, 0, stream>>>(u1_w, U1b, FF * DD / 4);
    cvt_bf16<<<2048, 256, 0, stream>>>(u2_w, U2b, FF * DD / 4);
    pack_w<<<HALF, 256, 0, stream>>>(v11, v12, b1, Wl);
    pack_w<<<HALF, 256, 0, stream>>>(v21, v22, b2, Wr);

    // U-GEMMs: x1raw -> Yl[:,0:4096], x2raw -> Yr[:,4096:8192]  (relu^2, bf16)
    gemm_bt<1><<<(TOK / 128) * (FF / 128), 256, 0, stream>>>(Xb, U1b, u1_b, Yl,      FF, DD, KCAT);
    gemm_bt<1><<<(TOK / 128) * (FF / 128), 256, 0, stream>>>(Xb, U2b, u2_b, Yr + FF, FF, DD, KCAT);

    // gating / tiny einsums
    glue<<<TOK, 256, 0, stream>>>(g1, g2, Yl, Yr);

    // V-GEMMs: out[:, 0:1024] = Yl @ Wl^T ; out[:, 1024:2048] = Yr @ Wr^T  (fp32)
    gemm_bt<0><<<(TOK / 128) * (HALF / 128), 256, 0, stream>>>(Yl, Wl, nullptr, out,        HALF, KCAT, DD);
    gemm_bt<0><<<(TOK / 128) * (HALF / 128), 256, 0, stream>>>(Yr, Wr, nullptr, out + HALF, HALF, KCAT, DD);
}

// Round 2
// 750.382 us; speedup vs baseline: 1.4225x; 1.4225x over previous
//
#include <hip/hip_runtime.h>
#include <hip/hip_bf16.h>

// MonetMoVDE: B=4 T=2048 D=2048 H=8 E=512 M=8, F=4096, HALF=1024
#define TOK   8192   // B*T
#define DD    2048
#define FF    4096
#define EE    512
#define HALF  1024
#define KCAT  8704   // F + F + E  (concat K for V-GEMMs, 8704 = 272*32)

typedef __bf16 bf16x8 __attribute__((ext_vector_type(8)));
typedef __bf16 bf16x4 __attribute__((ext_vector_type(4)));
typedef float  f32x4  __attribute__((ext_vector_type(4)));
using bf16 = __hip_bfloat16;

#define AS1(p) ((const __attribute__((address_space(1))) void*)(p))
#define AS3(p) ((__attribute__((address_space(3))) void*)(p))

// ---------------- prep kernels ----------------

__global__ void cvt_bf16(const float* __restrict__ in, bf16* __restrict__ out, int n4) {
    int i = blockIdx.x * blockDim.x + threadIdx.x;
    int stride = gridDim.x * blockDim.x;
    for (; i < n4; i += stride) {
        float4 v = ((const float4*)in)[i];
        bf16x4 o;
        o[0] = (__bf16)v.x; o[1] = (__bf16)v.y; o[2] = (__bf16)v.z; o[3] = (__bf16)v.w;
        ((bf16x4*)out)[i] = o;
    }
}

// W [1024][8704] = [vA | vB | bT]   (vA,vB: [1024][4096] f32; bmat: [512][1024] f32)
__global__ void pack_w(const float* __restrict__ vA, const float* __restrict__ vB,
                       const float* __restrict__ bmat, bf16* __restrict__ W) {
    int n = blockIdx.x;
    const float* ra = vA + (size_t)n * FF;
    const float* rb = vB + (size_t)n * FF;
    bf16* w = W + (size_t)n * KCAT;
    for (int k = threadIdx.x; k < FF; k += 256) {
        w[k]      = __float2bfloat16(ra[k]);
        w[FF + k] = __float2bfloat16(rb[k]);
    }
    for (int e = threadIdx.x; e < EE; e += 256)
        w[2 * FF + e] = __float2bfloat16(bmat[(size_t)e * HALF + n]);
}

// ---------------- GEMM: C[m,n] = sum_k A[m,k] * Bw[n,k] ----------------
// 256x256 tile, BK=32, 8 waves (2Mx4N), 16x16x32 bf16 MFMA.
// 3-buffer LDS ring, stage tile t+2 while computing tile t, counted vmcnt.
// LDS tile layout [256][32] bf16 with XOR swizzle byte ^= ((byte>>7)&3)<<4
// (applied via pre-swizzled global source; gload_lds dest stays linear).
// Fused dual-GEMM: blocks [0,npg) -> set 0, [npg,2npg) -> set 1.
// MODE 0: fp32 store.  MODE 1: relu(z+bias)^2 -> bf16 store.
template<int MODE>
__global__ __launch_bounds__(512, 2)
void gemm8(const bf16* __restrict__ A0, const bf16* __restrict__ B0,
           const float* __restrict__ bias0, void* __restrict__ C0,
           const bf16* __restrict__ A1, const bf16* __restrict__ B1,
           const float* __restrict__ bias1, void* __restrict__ C1,
           int nbm, int nbn, int K, int ldc)
{
    __shared__ __align__(16) char smem[3 * 32768];   // 3 x (A 16KB + B 16KB)
    const int tid  = threadIdx.x;
    const int lane = tid & 63;
    const int wid  = tid >> 6;
    const int wm = wid >> 2, wn = wid & 3;
    const int r16 = lane & 15, kb = lane >> 4;

    int bid = blockIdx.x;
    {   // bijective XCD swizzle (m204)
        int nwg = gridDim.x;
        int q = nwg >> 3, r = nwg & 7;
        int xcd = bid & 7, idx = bid >> 3;
        bid = (xcd < r ? xcd * (q + 1) : r * (q + 1) + (xcd - r) * q) + idx;
    }
    const int npg = nbm * nbn;
    const int g   = bid / npg;
    const int lb  = bid - g * npg;
    const int bm = lb / nbn, bn = lb - bm * nbn;

    const bf16*  A    = g ? A1 : A0;
    const bf16*  Bw   = g ? B1 : B0;
    const float* bias = g ? bias1 : bias0;
    char* Cout = (char*)(g ? C1 : C0);

    const long row0 = (long)bm * 256;
    const int  col0 = bn * 256;
    const int  nt   = K >> 5;

    // staging sources (pre-swizzled) + linear LDS dests
    const char* gp[4];
    uint32_t ldst[4];
    #pragma unroll
    for (int l = 0; l < 4; ++l) {
        const int ab = l >> 1;            // 0 = A, 1 = B
        const int li = l & 1;
        const uint32_t S = (uint32_t)(li * 512 + tid) * 16;   // linear 16B slot byte
        const uint32_t L = S ^ (((S >> 7) & 3) << 4);         // logical byte (involution)
        const int r  = (int)(L >> 6);
        const int c2 = (int)(L & 63);
        const bf16* src = ab ? (Bw + (long)(col0 + r) * K) : (A + (row0 + r) * (long)K);
        gp[l]   = (const char*)src + c2;
        ldst[l] = (uint32_t)(ab * 16384) + (uint32_t)((li * 512 + (tid & ~63)) * 16);
    }

    // per-lane LDS read base offsets (swizzled); frag i/j at +i*1024 / +j*1024
    uint32_t aoff, boff;
    {   int R0 = wm * 128 + r16;
        aoff = (uint32_t)((R0 * 64 + kb * 16) ^ (((R0 >> 1) & 3) << 4)); }
    {   int S0 = wn * 64 + r16;
        boff = 16384u + (uint32_t)((S0 * 64 + kb * 16) ^ (((S0 >> 1) & 3) << 4)); }

    f32x4 acc[8][4];
    #pragma unroll
    for (int i = 0; i < 8; ++i)
        #pragma unroll
        for (int j = 0; j < 4; ++j)
            acc[i][j] = (f32x4){0.f, 0.f, 0.f, 0.f};

    // prologue: stage tiles 0 (buf0) and 1 (buf1)
    #pragma unroll
    for (int tt = 0; tt < 2; ++tt)
        #pragma unroll
        for (int l = 0; l < 4; ++l)
            __builtin_amdgcn_global_load_lds(AS1(gp[l] + tt * 64),
                                             AS3(smem + tt * 32768 + ldst[l]), 16, 0, 0);
    #pragma unroll
    for (int l = 0; l < 4; ++l) gp[l] += 128;   // now points at tile 2

    int buf = 0;
    for (int t = 0; t < nt; ++t) {
        int sb = buf + 2; if (sb >= 3) sb -= 3;
        if (t + 2 < nt) {
            #pragma unroll
            for (int l = 0; l < 4; ++l) {
                __builtin_amdgcn_global_load_lds(AS1(gp[l]),
                                                 AS3(smem + sb * 32768 + ldst[l]), 16, 0, 0);
                gp[l] += 64;
            }
            // allow stages t+1,t+2 (8 loads) in flight; stage t retired -> readable
            asm volatile("s_waitcnt vmcnt(8)\n\ts_barrier" ::: "memory");
        } else if (t + 2 == nt) {
            asm volatile("s_waitcnt vmcnt(4)\n\ts_barrier" ::: "memory");
        } else {
            asm volatile("s_waitcnt vmcnt(0)\n\ts_barrier" ::: "memory");
        }

        const char* pb = smem + buf * 32768;
        bf16x8 af[8], bv[4];
        #pragma unroll
        for (int i = 0; i < 8; ++i)
            af[i] = *(const bf16x8*)(pb + aoff + i * 1024);
        #pragma unroll
        for (int j = 0; j < 4; ++j)
            bv[j] = *(const bf16x8*)(pb + boff + j * 1024);

        __builtin_amdgcn_s_setprio(1);
        #pragma unroll
        for (int i = 0; i < 8; ++i)
            #pragma unroll
            for (int j = 0; j < 4; ++j)
                acc[i][j] = __builtin_amdgcn_mfma_f32_16x16x32_bf16(af[i], bv[j], acc[i][j], 0, 0, 0);
        __builtin_amdgcn_s_setprio(0);

        // separate iter-t LDS reads from iter-t+1 stage issues into this buffer
        asm volatile("s_barrier" ::: "memory");
        buf = (buf == 2) ? 0 : buf + 1;
    }

    // epilogue: row = row0 + wm*128 + i*16 + (lane>>4)*4 + e ; col = col0 + wn*64 + j*16 + r16
    const int rb = (lane >> 4) * 4;
    #pragma unroll
    for (int i = 0; i < 8; ++i) {
        #pragma unroll
        for (int j = 0; j < 4; ++j) {
            const int cc = col0 + wn * 64 + j * 16 + r16;
            float badd = 0.f;
            if (MODE == 1) badd = bias[cc];
            #pragma unroll
            for (int e = 0; e < 4; ++e) {
                long row = row0 + wm * 128 + i * 16 + rb + e;
                float v = acc[i][j][e];
                if (MODE == 1) {
                    v += badd;
                    v = fmaxf(v, 0.f);
                    v = v * v;
                    ((bf16*)Cout)[row * ldc + cc] = __float2bfloat16(v);
                } else {
                    ((float*)Cout)[row * ldc + cc] = v;
                }
            }
        }
    }
}

// ---------------- glue: per-token gating / tiny einsums ----------------
// In:  g1,g2 [TOK][8][512] f32; Yl[:,0:4096]=x1 raw bf16; Yr[:,4096:8192]=x2 raw bf16
// Out: Yl = [x1*g1s | y12 | g1s]; Yr = [y21 | x2*g2s | g2s]  (all bf16)
#define GPAD 524   // 8-row pad: h-stride hits 8 distinct banks; 524*4%16==0
__global__ __launch_bounds__(256)
void glue(const float* __restrict__ g1, const float* __restrict__ g2,
          bf16* __restrict__ Yl, bf16* __restrict__ Yr)
{
    __shared__ __align__(16) float g1t[8 * GPAD];
    __shared__ __align__(16) float g2t[8 * GPAD];
    __shared__ float g1s[EE], g2s[EE];
    __shared__ float t1s[64], t2s[64];
    __shared__ float t1p[4][64], t2p[4][64];
    __shared__ __align__(16) bf16 x1t[FF], x2t[FF];

    const int t   = blockIdx.x;
    const int tid = threadIdx.x;
    const float* g1p = g1 + (size_t)t * FF;
    const float* g2p = g2 + (size_t)t * FF;
    bf16* ylp = Yl + (size_t)t * KCAT;
    bf16* yrp = Yr + (size_t)t * KCAT;

    #pragma unroll
    for (int c = 0; c < 4; ++c) {
        int idx4 = (c * 256 + tid) * 4;
        float4 v1 = *(const float4*)(g1p + idx4);
        float4 v2 = *(const float4*)(g2p + idx4);
        int h = idx4 >> 9, e = idx4 & 511;
        *(float4*)&g1t[h * GPAD + e] = v1;
        *(float4*)&g2t[h * GPAD + e] = v2;
    }
    #pragma unroll
    for (int c = 0; c < 2; ++c) {
        int idx8 = (c * 256 + tid) * 8;
        *(bf16x8*)&x1t[idx8] = *(const bf16x8*)(ylp + idx8);
        *(bf16x8*)&x2t[idx8] = *(const bf16x8*)(yrp + FF + idx8);
    }
    __syncthreads();

    #pragma unroll
    for (int c = 0; c < 2; ++c) {
        int e = c * 256 + tid;
        float s1 = 0.f, s2 = 0.f;
        #pragma unroll
        for (int h = 0; h < 8; ++h) { s1 += g1t[h * GPAD + e]; s2 += g2t[h * GPAD + e]; }
        g1s[e] = s1; g2s[e] = s2;
    }

    {   // t1[h,m] = sum_e x1[e,m]*g1[h,e] ; t2 likewise. 4-way partials.
        int o = tid & 63;
        int h = o & 7, m = o >> 3;
        int p = tid >> 6;
        float s1 = 0.f, s2 = 0.f;
        #pragma unroll 8
        for (int ii = 0; ii < 128; ++ii) {
            int e = p * 128 + ii;
            float xv1 = __bfloat162float(x1t[e * 8 + m]);
            float xv2 = __bfloat162float(x2t[e * 8 + m]);
            s1 += xv1 * g1t[h * GPAD + e];
            s2 += xv2 * g2t[h * GPAD + e];
        }
        t1p[p][o] = s1; t2p[p][o] = s2;
    }
    __syncthreads();
    if (tid < 64)       t1s[tid] = t1p[0][tid] + t1p[1][tid] + t1p[2][tid] + t1p[3][tid];
    else if (tid < 128) { int o = tid - 64; t2s[o] = t2p[0][o] + t2p[1][o] + t2p[2][o] + t2p[3][o]; }
    __syncthreads();

    #pragma unroll
    for (int c = 0; c < 2; ++c) {
        int f0 = (c * 256 + tid) * 8;
        int e  = f0 >> 3;
        float s1 = g1s[e], s2 = g2s[e];
        bf16x8 xa = *(const bf16x8*)&x1t[f0];
        bf16x8 xb = *(const bf16x8*)&x2t[f0];
        bf16x8 o1, o2;
        #pragma unroll
        for (int u = 0; u < 8; ++u) {
            o1[u] = (__bf16)((float)xa[u] * s1);
            o2[u] = (__bf16)((float)xb[u] * s2);
        }
        *(bf16x8*)(ylp + f0)      = o1;
        *(bf16x8*)(yrp + FF + f0) = o2;
    }
    #pragma unroll
    for (int c = 0; c < 2; ++c) {
        int f0 = (c * 256 + tid) * 8;
        int i  = f0 >> 3;
        bf16x8 o12v, o21v;
        #pragma unroll
        for (int m = 0; m < 8; ++m) {
            float s12 = 0.f, s21 = 0.f;
            #pragma unroll
            for (int h = 0; h < 8; ++h) {
                s12 += t2s[(m << 3) | h] * g1t[h * GPAD + i];
                s21 += t1s[(m << 3) | h] * g2t[h * GPAD + i];
            }
            o12v[m] = (__bf16)s12;
            o21v[m] = (__bf16)s21;
        }
        *(bf16x8*)(ylp + FF + f0) = o12v;
        *(bf16x8*)(yrp + f0)      = o21v;
    }
    {
        int e0 = tid * 2;
        ylp[2 * FF + e0]     = __float2bfloat16(g1s[e0]);
        ylp[2 * FF + e0 + 1] = __float2bfloat16(g1s[e0 + 1]);
        yrp[2 * FF + e0]     = __float2bfloat16(g2s[e0]);
        yrp[2 * FF + e0 + 1] = __float2bfloat16(g2s[e0 + 1]);
    }
}

// ---------------- launch ----------------

extern "C" void kernel_launch(void* const* d_in, const int* in_sizes, int n_in,
                              void* d_out, int out_size, void* d_ws, size_t ws_size,
                              hipStream_t stream) {
    const float* x    = (const float*)d_in[0];
    const float* g1   = (const float*)d_in[1];
    const float* g2   = (const float*)d_in[2];
    const float* u1_w = (const float*)d_in[3];
    const float* u1_b = (const float*)d_in[4];
    const float* u2_w = (const float*)d_in[5];
    const float* u2_b = (const float*)d_in[6];
    const float* v11  = (const float*)d_in[7];
    const float* v12  = (const float*)d_in[8];
    const float* v21  = (const float*)d_in[9];
    const float* v22  = (const float*)d_in[10];
    const float* b1   = (const float*)d_in[11];
    const float* b2   = (const float*)d_in[12];
    float* out = (float*)d_out;

    size_t off = 0;
    char* base = (char*)d_ws;
    auto take = [&](size_t bytes) { void* p = base + off; off += (bytes + 255) & ~(size_t)255; return p; };
    bf16* Xb  = (bf16*)take((size_t)TOK * DD * 2);
    bf16* U1b = (bf16*)take((size_t)FF * DD * 2);
    bf16* U2b = (bf16*)take((size_t)FF * DD * 2);
    bf16* Wl  = (bf16*)take((size_t)HALF * KCAT * 2);
    bf16* Wr  = (bf16*)take((size_t)HALF * KCAT * 2);
    bf16* Yl  = (bf16*)take((size_t)TOK * KCAT * 2);
    bf16* Yr  = (bf16*)take((size_t)TOK * KCAT * 2);

    // prep
    cvt_bf16<<<4096, 256, 0, stream>>>(x,    Xb,  TOK * DD / 4);
    cvt_bf16<<<2048, 256, 0, stream>>>(u1_w, U1b, FF * DD / 4);
    cvt_bf16<<<2048, 256, 0, stream>>>(u2_w, U2b, FF * DD / 4);
    pack_w<<<HALF, 256, 0, stream>>>(v11, v12, b1, Wl);
    pack_w<<<HALF, 256, 0, stream>>>(v21, v22, b2, Wr);

    // fused U-GEMMs: x1raw -> Yl[:,0:4096], x2raw -> Yr[:,4096:8192]  (relu^2, bf16)
    gemm8<1><<<2 * (TOK / 256) * (FF / 256), 512, 0, stream>>>(
        Xb, U1b, u1_b, Yl,
        Xb, U2b, u2_b, Yr + FF,
        TOK / 256, FF / 256, DD, KCAT);

    // gating / tiny einsums
    glue<<<TOK, 256, 0, stream>>>(g1, g2, Yl, Yr);

    // fused V-GEMMs: out[:,0:1024] = Yl @ Wl^T ; out[:,1024:2048] = Yr @ Wr^T  (fp32)
    gemm8<0><<<2 * (TOK / 256) * (HALF / 256), 512, 0, stream>>>(
        Yl, Wl, nullptr, out,
        Yr, Wr, nullptr, out + HALF,
        TOK / 256, HALF / 256, KCAT, DD);
}